// Round 1
// baseline (383.772 us; speedup 1.0000x reference)
//
#include <hip/hip_runtime.h>
#include <hip/hip_bf16.h>

typedef __attribute__((ext_vector_type(4))) float f32x4;
typedef __attribute__((ext_vector_type(8))) __bf16 bf16x8;
typedef __attribute__((ext_vector_type(4))) unsigned short us4;
typedef __attribute__((ext_vector_type(4))) unsigned int u32x4;

#define LDS_AS __attribute__((address_space(3)))
#define GLB_AS __attribute__((address_space(1)))

__device__ __forceinline__ unsigned short f2bf(float f) {
    unsigned u = __builtin_bit_cast(unsigned, f);
    return (unsigned short)((u + 0x7FFFu + ((u >> 16) & 1u)) >> 16);  // RNE
}
__device__ __forceinline__ float bf2f(unsigned short h) {
    return __builtin_bit_cast(float, (unsigned)h << 16);
}
__device__ __forceinline__ void cp16(const void* g, void* l) {
    __builtin_amdgcn_global_load_lds((const GLB_AS unsigned int*)g,
                                     (LDS_AS unsigned int*)l, 16, 0, 0);
}

// ---------------------------------------------------------------- prep
// casts frames/vecs/weights to bf16 (frames K padded 600->608),
// pads Wout1 [768][1539] -> [768][1792], zeroes h1acc/h2acc.
__global__ __launch_bounds__(256) void prep_kernel(
    const float* __restrict__ frames, const float* __restrict__ Wfk, const float* __restrict__ Wfv,
    const float* __restrict__ vecs, const float* __restrict__ Wvk, const float* __restrict__ Wvv,
    const float* __restrict__ Wout1,
    unsigned short* __restrict__ fbf, unsigned short* __restrict__ wf,
    unsigned short* __restrict__ vbf, unsigned short* __restrict__ wv,
    float* __restrict__ W1p, float* __restrict__ hacc)
{
    int i = blockIdx.x * 256 + threadIdx.x;
    if (i < 2490368) {                       // frames: 16384 x 152 items (4 cols each)
        int row = i / 152, k = (i - row * 152) * 4;
        us4 o = {0, 0, 0, 0};
        if (k < 600) {
            f32x4 v = *(const f32x4*)(frames + (size_t)row * 600 + k);
            o[0] = f2bf(v[0]); o[1] = f2bf(v[1]); o[2] = f2bf(v[2]); o[3] = f2bf(v[3]);
        }
        *(us4*)(fbf + (size_t)row * 608 + k) = o;
        return;
    }
    i -= 2490368;
    if (i < 155648) {                        // wf: 1024 x 152 (rows 0-511 Wfk, 512-1023 Wfv)
        int row = i / 152, k = (i - row * 152) * 4;
        const float* src = row < 512 ? Wfk + (size_t)row * 600 : Wfv + (size_t)(row - 512) * 600;
        us4 o = {0, 0, 0, 0};
        if (k < 600) {
            f32x4 v = *(const f32x4*)(src + k);
            o[0] = f2bf(v[0]); o[1] = f2bf(v[1]); o[2] = f2bf(v[2]); o[3] = f2bf(v[3]);
        }
        *(us4*)(wf + (size_t)row * 608 + k) = o;
        return;
    }
    i -= 155648;
    if (i < 1572864) {                       // vecs: 8192 x 192
        int row = i / 192, k = (i - row * 192) * 4;
        f32x4 v = *(const f32x4*)(vecs + (size_t)row * 768 + k);
        us4 o = {f2bf(v[0]), f2bf(v[1]), f2bf(v[2]), f2bf(v[3])};
        *(us4*)(vbf + (size_t)row * 768 + k) = o;
        return;
    }
    i -= 1572864;
    if (i < 196608) {                        // wv: 1024 x 192
        int row = i / 192, k = (i - row * 192) * 4;
        const float* src = row < 512 ? Wvk + (size_t)row * 768 : Wvv + (size_t)(row - 512) * 768;
        f32x4 v = *(const f32x4*)(src + k);
        us4 o = {f2bf(v[0]), f2bf(v[1]), f2bf(v[2]), f2bf(v[3])};
        *(us4*)(wv + (size_t)row * 768 + k) = o;
        return;
    }
    i -= 196608;
    if (i < 344064) {                        // W1p: 768 x 448 float4 items
        int r = i / 448, k = (i - r * 448) * 4;
        f32x4 o;
        #pragma unroll
        for (int j = 0; j < 4; ++j) {
            int kk = k + j;
            o[j] = kk < 1539 ? Wout1[(size_t)r * 1539 + kk] : 0.f;
        }
        *(f32x4*)(W1p + (size_t)r * 1792 + k) = o;
        return;
    }
    i -= 344064;
    if (i < 20480) {                         // zero h1acc+h2acc (81920 floats)
        f32x4 z = {0, 0, 0, 0};
        *(f32x4*)(hacc + (size_t)i * 4) = z;
    }
}

// ---------------------------------------------------------------- GEMM (m97 structure)
// C[m][n] = relu(sum_k A[m][k]*B[n][k]), A [M][Kp] bf16, B [1024][Kp] bf16, C [M][1024] bf16
__global__ __launch_bounds__(256) void gemm_bt_relu(
    const unsigned short* __restrict__ A, const unsigned short* __restrict__ B,
    unsigned short* __restrict__ C, int Kp)
{
    __shared__ alignas(16) unsigned short sA[128 * 32];
    __shared__ alignas(16) unsigned short sB[128 * 32];
    const int t = threadIdx.x;
    const int w = t >> 6, l = t & 63;
    const int bm = blockIdx.x >> 3, bn = blockIdx.x & 7;
    const int m0 = bm << 7, n0 = bn << 7;

    const int srow = t >> 2, sk0 = (t & 3) << 3;
    const unsigned short* gA = A + (size_t)(m0 + srow) * Kp + sk0;
    const unsigned short* gB = B + (size_t)(n0 + srow) * Kp + sk0;
    char* lA = (char*)sA + w * 1024;
    char* lB = (char*)sB + w * 1024;

    const int wr = w >> 1, wc = w & 1;
    const unsigned short* pA = sA + (size_t)((wr * 64 + (l & 15)) * 32 + ((l >> 4) << 3));
    const unsigned short* pB = sB + (size_t)((wc * 64 + (l & 15)) * 32 + ((l >> 4) << 3));

    f32x4 acc[4][4] = {};
    const int ksteps = Kp >> 5;
    for (int kt = 0; kt < ksteps; ++kt) {
        const unsigned short* ga = gA + kt * 32;
        const unsigned short* gb = gB + kt * 32;
        cp16(ga, lA);
        cp16(ga + (size_t)64 * Kp, lA + 4096);
        cp16(gb, lB);
        cp16(gb + (size_t)64 * Kp, lB + 4096);
        __syncthreads();
        bf16x8 af[4], bfr[4];
        #pragma unroll
        for (int i = 0; i < 4; ++i) {
            af[i]  = *(const bf16x8*)(pA + i * 512);
            bfr[i] = *(const bf16x8*)(pB + i * 512);
        }
        #pragma unroll
        for (int mi = 0; mi < 4; ++mi)
            #pragma unroll
            for (int ni = 0; ni < 4; ++ni)
                acc[mi][ni] = __builtin_amdgcn_mfma_f32_16x16x32_bf16(af[mi], bfr[ni], acc[mi][ni], 0, 0, 0);
        __syncthreads();
    }
    const int crow0 = m0 + wr * 64 + ((l >> 4) << 2);
    const int ccol0 = n0 + wc * 64 + (l & 15);
    #pragma unroll
    for (int mi = 0; mi < 4; ++mi)
        #pragma unroll
        for (int ni = 0; ni < 4; ++ni)
            #pragma unroll
            for (int j = 0; j < 4; ++j) {
                float v = acc[mi][ni][j];
                v = v > 0.f ? v : 0.f;
                C[(size_t)(crow0 + mi * 16 + j) * 1024 + (ccol0 + ni * 16)] = f2bf(v);
            }
}

// ---------------------------------------------------------------- group sums + a_v
__global__ __launch_bounds__(256) void sums_kernel(
    const unsigned short* __restrict__ Cf, const unsigned short* __restrict__ Cv,
    const float* __restrict__ audios, const float* __restrict__ Wav,
    float* __restrict__ f_q_p, float* __restrict__ v_q_p,
    float* __restrict__ a_v, float* __restrict__ a_q_p)
{
    __shared__ float aud[128];
    const int t = threadIdx.x, blk = blockIdx.x;
    if (blk < 128) {
        const int isv = blk >> 6;
        const int b = blk & 63;
        const int NF = isv ? 128 : 256;
        const unsigned short* X = isv ? Cv : Cf;
        const unsigned int* p = (const unsigned int*)(X + ((size_t)b * NF) * 1024 + 512) + t;
        float s0 = 0.f, s1 = 0.f;
        for (int f = 0; f < NF; ++f) {
            unsigned u = p[(size_t)f * 512];
            s0 += bf2f((unsigned short)(u & 0xffff));
            s1 += bf2f((unsigned short)(u >> 16));
        }
        float* outp = isv ? v_q_p : f_q_p;
        outp[b * 512 + 2 * t]     = s0;
        outp[b * 512 + 2 * t + 1] = s1;
    } else {
        const int b = blk - 128;
        if (t < 128) aud[t] = audios[b * 128 + t];
        __syncthreads();
        #pragma unroll
        for (int cc = 0; cc < 2; ++cc) {
            int c = 2 * t + cc;
            const float* wr = Wav + (size_t)c * 128;
            float s = 0.f;
            #pragma unroll
            for (int k4 = 0; k4 < 32; ++k4) {
                f32x4 wvv = *(const f32x4*)(wr + k4 * 4);
                s += wvv[0] * aud[k4 * 4] + wvv[1] * aud[k4 * 4 + 1]
                   + wvv[2] * aud[k4 * 4 + 2] + wvv[3] * aud[k4 * 4 + 3];
            }
            s = s > 0.f ? s : 0.f;
            a_v[b * 512 + c] = s;
            a_q_p[b * 512 + c] = s;
        }
    }
}

// ---------------------------------------------------------------- attention (per group)
__global__ __launch_bounds__(256) void attn_kernel(
    const unsigned short* __restrict__ Cf, const unsigned short* __restrict__ Cv,
    const float* __restrict__ v_q_p, float* __restrict__ fc, float* __restrict__ vc)
{
    __shared__ float vq[512];
    __shared__ float sc[256];
    __shared__ float red[256];
    const int t = threadIdx.x;
    const int isv = blockIdx.x >> 6;
    const int b = blockIdx.x & 63;
    const int NF = isv ? 128 : 256;
    const unsigned short* X = isv ? Cv : Cf;
    float* outp = isv ? vc : fc;

    vq[t] = v_q_p[b * 512 + t];
    vq[t + 256] = v_q_p[b * 512 + t + 256];
    __syncthreads();

    float sv = -1e30f;
    if (t < NF) {
        const u32x4* p = (const u32x4*)(X + (size_t)(b * NF + t) * 1024);
        float acc = 0.f;
        for (int it = 0; it < 64; ++it) {
            u32x4 u = p[it];
            #pragma unroll
            for (int j = 0; j < 4; ++j) {
                unsigned uu = u[j];
                acc += bf2f((unsigned short)(uu & 0xffff)) * vq[it * 8 + 2 * j]
                     + bf2f((unsigned short)(uu >> 16))    * vq[it * 8 + 2 * j + 1];
            }
        }
        sv = acc * (1.f / 512.f);
    }
    sc[t] = sv;
    red[t] = sv;
    __syncthreads();
    for (int s = 128; s > 0; s >>= 1) {
        if (t < s) red[t] = fmaxf(red[t], red[t + s]);
        __syncthreads();
    }
    float m = red[0];
    __syncthreads();
    float pv = (t < NF) ? expf(sv - m) : 0.f;
    sc[t] = pv;
    red[t] = pv;
    __syncthreads();
    for (int s = 128; s > 0; s >>= 1) {
        if (t < s) red[t] += red[t + s];
        __syncthreads();
    }
    float inv = 1.f / red[0];
    // weighted sum of value half (cols 512..1023), 2 channels/thread
    const unsigned int* q = (const unsigned int*)X + (size_t)(b * NF) * 512 + 256 + t;
    float s0 = 0.f, s1 = 0.f;
    for (int f = 0; f < NF; ++f) {
        float a = sc[f];
        unsigned u = q[(size_t)f * 512];
        s0 += a * bf2f((unsigned short)(u & 0xffff));
        s1 += a * bf2f((unsigned short)(u >> 16));
    }
    outp[b * 512 + 2 * t]     = s0 * inv;
    outp[b * 512 + 2 * t + 1] = s1 * inv;
}

// ---------------------------------------------------------------- FF update: y += x_c @ W^T
__global__ __launch_bounds__(512) void update_kernel(
    const float* __restrict__ Wff_f, const float* __restrict__ Wff_v, const float* __restrict__ Wff_a,
    int iter, const float* __restrict__ fc, const float* __restrict__ vc, const float* __restrict__ a_v,
    float* __restrict__ f_q_p, float* __restrict__ v_q_p, float* __restrict__ a_q_p)
{
    __shared__ float xs[32 * 64];
    const int t = threadIdx.x;
    const int op = blockIdx.x >> 4;
    const int rc = (blockIdx.x >> 1) & 7;
    const int bh = blockIdx.x & 1;
    const float* W = (op == 0 ? Wff_f : op == 1 ? Wff_v : Wff_a) + (size_t)iter * 512 * 512;
    const float* x = op == 0 ? fc : op == 1 ? vc : a_v;
    float* y = op == 0 ? f_q_p : op == 1 ? v_q_p : a_q_p;
    const int r = t & 63, bg = t >> 6;
    const int r0 = rc * 64;
    float acc[4] = {0.f, 0.f, 0.f, 0.f};
    for (int ks = 0; ks < 512; ks += 64) {
        #pragma unroll
        for (int j = 0; j < 4; ++j) {
            int idx = t + j * 512;
            xs[idx] = x[(size_t)(bh * 32 + (idx >> 6)) * 512 + ks + (idx & 63)];
        }
        __syncthreads();
        const float* wrow = W + (size_t)(r0 + r) * 512 + ks;
        #pragma unroll
        for (int k4 = 0; k4 < 16; ++k4) {
            f32x4 wvv = *(const f32x4*)(wrow + k4 * 4);
            #pragma unroll
            for (int bb = 0; bb < 4; ++bb) {
                f32x4 xv = *(const f32x4*)(xs + (bg * 4 + bb) * 64 + k4 * 4);
                acc[bb] += wvv[0] * xv[0] + wvv[1] * xv[1] + wvv[2] * xv[2] + wvv[3] * xv[3];
            }
        }
        __syncthreads();
    }
    #pragma unroll
    for (int bb = 0; bb < 4; ++bb) {
        int b = bh * 32 + bg * 4 + bb;
        y[(size_t)b * 512 + r0 + r] += acc[bb];
    }
}

// ---------------------------------------------------------------- normalize + build feats
__global__ __launch_bounds__(512) void normfeats_kernel(
    const float* __restrict__ a_q_p, const float* __restrict__ f_q_p, const float* __restrict__ v_q_p,
    const float* __restrict__ metas, float* __restrict__ feats)
{
    __shared__ float red[512];
    const int t = threadIdx.x, b = blockIdx.x;
    float a = a_q_p[b * 512 + t];
    red[t] = a;
    __syncthreads();
    for (int s = 256; s > 0; s >>= 1) { if (t < s) red[t] += red[t + s]; __syncthreads(); }
    float mean = red[0] * (1.f / 512.f);
    __syncthreads();
    float d = a - mean;
    red[t] = d * d;
    __syncthreads();
    for (int s = 256; s > 0; s >>= 1) { if (t < s) red[t] += red[t + s]; __syncthreads(); }
    float sd = sqrtf(red[0] * (1.f / 511.f));
    float* fr = feats + (size_t)b * 1792;
    fr[t]        = f_q_p[b * 512 + t];
    fr[512 + t]  = v_q_p[b * 512 + t];
    fr[1024 + t] = d / sd;
    if (t < 256) {
        float v = 0.f;
        if (t == 0) v = metas[b * 5 + 1] * (1.f / 1500.f);
        else if (t == 1) v = metas[b * 5 + 4] * 0.2f;
        else if (t == 2) {
            float du = metas[b * 5 + 3] - metas[b * 5 + 2];
            v = (du > 8000.f ? 100.f : du) * 0.01f;
        }
        fr[1536 + t] = v;
    }
}

// ---------------------------------------------------------------- MLP layer 1 (k-split + atomics)
__global__ __launch_bounds__(512) void mlp1_kernel(
    const float* __restrict__ feats, const float* __restrict__ W1p, float* __restrict__ h1acc)
{
    __shared__ float xs[64 * 64];
    const int t = threadIdx.x;
    const int nc = blockIdx.x % 12, kc = blockIdx.x / 12;
    const int r = t & 63, bg = t >> 6;
    const int r0 = nc * 64;
    const float* wrow = W1p + (size_t)(r0 + r) * 1792 + kc * 448;
    float acc[8] = {};
    for (int s = 0; s < 7; ++s) {
        const int ke = kc * 448 + s * 64;
        #pragma unroll
        for (int j = 0; j < 8; ++j) {
            int idx = t + j * 512;
            xs[idx] = feats[(size_t)(idx >> 6) * 1792 + ke + (idx & 63)];
        }
        __syncthreads();
        #pragma unroll
        for (int k4 = 0; k4 < 16; ++k4) {
            f32x4 wvv = *(const f32x4*)(wrow + s * 64 + k4 * 4);
            #pragma unroll
            for (int bb = 0; bb < 8; ++bb) {
                f32x4 xv = *(const f32x4*)(xs + (bg * 8 + bb) * 64 + k4 * 4);
                acc[bb] += wvv[0] * xv[0] + wvv[1] * xv[1] + wvv[2] * xv[2] + wvv[3] * xv[3];
            }
        }
        __syncthreads();
    }
    #pragma unroll
    for (int bb = 0; bb < 8; ++bb)
        atomicAdd(&h1acc[(size_t)(bg * 8 + bb) * 768 + r0 + r], acc[bb]);
}

// ---------------------------------------------------------------- MLP layer 2
__global__ __launch_bounds__(512) void mlp2_kernel(
    const float* __restrict__ h1acc, const float* __restrict__ W2, float* __restrict__ h2acc)
{
    __shared__ float xs[64 * 64];
    const int t = threadIdx.x;
    const int nc = blockIdx.x & 7, kc = blockIdx.x >> 3;
    const int r = t & 63, bg = t >> 6;
    const int r0 = nc * 64;
    const float* wrow = W2 + (size_t)(r0 + r) * 768 + kc * 192;
    float acc[8] = {};
    for (int s = 0; s < 3; ++s) {
        const int ke = kc * 192 + s * 64;
        #pragma unroll
        for (int j = 0; j < 8; ++j) {
            int idx = t + j * 512;
            float v = h1acc[(size_t)(idx >> 6) * 768 + ke + (idx & 63)];
            xs[idx] = v > 0.f ? v : 0.f;
        }
        __syncthreads();
        #pragma unroll
        for (int k4 = 0; k4 < 16; ++k4) {
            f32x4 wvv = *(const f32x4*)(wrow + s * 64 + k4 * 4);
            #pragma unroll
            for (int bb = 0; bb < 8; ++bb) {
                f32x4 xv = *(const f32x4*)(xs + (bg * 8 + bb) * 64 + k4 * 4);
                acc[bb] += wvv[0] * xv[0] + wvv[1] * xv[1] + wvv[2] * xv[2] + wvv[3] * xv[3];
            }
        }
        __syncthreads();
    }
    #pragma unroll
    for (int bb = 0; bb < 8; ++bb)
        atomicAdd(&h2acc[(size_t)(bg * 8 + bb) * 512 + r0 + r], acc[bb]);
}

// ---------------------------------------------------------------- MLP layers 3+4 fused
__global__ __launch_bounds__(512) void mlp34_kernel(
    const float* __restrict__ h2acc, const float* __restrict__ W3, const float* __restrict__ W4,
    float* __restrict__ out)
{
    __shared__ float xs[8 * 512];
    __shared__ float h3s[8 * 64];
    const int t = threadIdx.x, blk = blockIdx.x;
    #pragma unroll
    for (int j = 0; j < 8; ++j) {
        int idx = t + j * 512;
        float v = h2acc[(size_t)(blk * 8 + (idx >> 9)) * 512 + (idx & 511)];
        xs[idx] = v > 0.f ? v : 0.f;
    }
    __syncthreads();
    const int r = t & 63, bg = t >> 6;
    const float* wrow = W3 + (size_t)r * 512;
    float acc = 0.f;
    #pragma unroll 8
    for (int k4 = 0; k4 < 128; ++k4) {
        f32x4 wvv = *(const f32x4*)(wrow + k4 * 4);
        f32x4 xv  = *(const f32x4*)(xs + bg * 512 + k4 * 4);
        acc += wvv[0] * xv[0] + wvv[1] * xv[1] + wvv[2] * xv[2] + wvv[3] * xv[3];
    }
    h3s[bg * 64 + r] = acc > 0.f ? acc : 0.f;
    __syncthreads();
    if (t < 8) {
        float s = 0.f;
        #pragma unroll 8
        for (int rr = 0; rr < 64; ++rr) s += h3s[t * 64 + rr] * W4[rr];
        out[blk * 8 + t] = 1.f / (1.f + expf(-s));
    }
}

// ---------------------------------------------------------------- launch
extern "C" void kernel_launch(void* const* d_in, const int* in_sizes, int n_in,
                              void* d_out, int out_size, void* d_ws, size_t ws_size,
                              hipStream_t stream)
{
    const float* metas  = (const float*)d_in[0];
    const float* frames = (const float*)d_in[2];
    const float* vecs   = (const float*)d_in[4];
    const float* audios = (const float*)d_in[6];
    const float* Wfk   = (const float*)d_in[8];
    const float* Wfv   = (const float*)d_in[9];
    const float* Wvk   = (const float*)d_in[10];
    const float* Wvv   = (const float*)d_in[11];
    const float* Wav   = (const float*)d_in[12];
    const float* Wff_f = (const float*)d_in[13];
    const float* Wff_v = (const float*)d_in[14];
    const float* Wff_a = (const float*)d_in[15];
    const float* Wout2 = (const float*)d_in[17];
    const float* Wout3 = (const float*)d_in[18];
    const float* Wout4 = (const float*)d_in[19];
    const float* Wout1 = (const float*)d_in[16];
    float* out = (float*)d_out;

    char* p = (char*)d_ws;
    auto alloc = [&](size_t n) { char* r = p; p += (n + 255) & ~(size_t)255; return r; };
    unsigned short* fbf = (unsigned short*)alloc(16384ull * 608 * 2);
    unsigned short* wf  = (unsigned short*)alloc(1024ull * 608 * 2);
    unsigned short* vbf = (unsigned short*)alloc(8192ull * 768 * 2);
    unsigned short* wv  = (unsigned short*)alloc(1024ull * 768 * 2);
    unsigned short* Cf  = (unsigned short*)alloc(16384ull * 1024 * 2);
    unsigned short* Cv  = (unsigned short*)alloc(8192ull * 1024 * 2);
    float* W1p   = (float*)alloc(768ull * 1792 * 4);
    float* feats = (float*)alloc(64ull * 1792 * 4);
    float* f_q_p = (float*)alloc(64ull * 512 * 4);
    float* v_q_p = (float*)alloc(64ull * 512 * 4);
    float* a_q_p = (float*)alloc(64ull * 512 * 4);
    float* a_v   = (float*)alloc(64ull * 512 * 4);
    float* fcb   = (float*)alloc(64ull * 512 * 4);
    float* vcb   = (float*)alloc(64ull * 512 * 4);
    float* hacc  = (float*)alloc(81920ull * 4);     // h1acc (64*768) | h2acc (64*512)
    float* h1acc = hacc;
    float* h2acc = hacc + 64 * 768;

    prep_kernel<<<18672, 256, 0, stream>>>(frames, Wfk, Wfv, vecs, Wvk, Wvv, Wout1,
                                           fbf, wf, vbf, wv, W1p, hacc);
    gemm_bt_relu<<<1024, 256, 0, stream>>>(fbf, wf, Cf, 608);
    gemm_bt_relu<<<512, 256, 0, stream>>>(vbf, wv, Cv, 768);
    sums_kernel<<<192, 256, 0, stream>>>(Cf, Cv, audios, Wav, f_q_p, v_q_p, a_v, a_q_p);
    for (int i = 0; i < 2; ++i) {
        attn_kernel<<<128, 256, 0, stream>>>(Cf, Cv, v_q_p, fcb, vcb);
        update_kernel<<<48, 512, 0, stream>>>(Wff_f, Wff_v, Wff_a, i, fcb, vcb, a_v,
                                              f_q_p, v_q_p, a_q_p);
    }
    normfeats_kernel<<<64, 512, 0, stream>>>(a_q_p, f_q_p, v_q_p, metas, feats);
    mlp1_kernel<<<48, 512, 0, stream>>>(feats, W1p, h1acc);
    mlp2_kernel<<<32, 512, 0, stream>>>(h1acc, Wout2, h2acc);
    mlp34_kernel<<<8, 512, 0, stream>>>(h2acc, Wout3, Wout4, out);
}

// Round 2
// 192.536 us; speedup vs baseline: 1.9933x; 1.9933x over previous
//
#include <hip/hip_runtime.h>
#include <hip/hip_bf16.h>

typedef __attribute__((ext_vector_type(4))) float f32x4;
typedef __attribute__((ext_vector_type(8))) __bf16 bf16x8;
typedef __attribute__((ext_vector_type(4))) unsigned short us4;
typedef __attribute__((ext_vector_type(4))) unsigned int u32x4;

#define LDS_AS __attribute__((address_space(3)))
#define GLB_AS __attribute__((address_space(1)))

__device__ __forceinline__ unsigned short f2bf(float f) {
    unsigned u = __builtin_bit_cast(unsigned, f);
    return (unsigned short)((u + 0x7FFFu + ((u >> 16) & 1u)) >> 16);  // RNE
}
__device__ __forceinline__ float bf2f(unsigned short h) {
    return __builtin_bit_cast(float, (unsigned)h << 16);
}
__device__ __forceinline__ void cp16(const void* g, void* l) {
    __builtin_amdgcn_global_load_lds((const GLB_AS unsigned int*)g,
                                     (LDS_AS unsigned int*)l, 16, 0, 0);
}

// ---------------------------------------------------------------- prep
// casts frames/vecs/weights to bf16 (frames K padded 600->608),
// pads Wout1 [768][1539] -> [768][1792], zeroes h1acc/h2acc and f_q_p/v_q_p.
__global__ __launch_bounds__(256) void prep_kernel(
    const float* __restrict__ frames, const float* __restrict__ Wfk, const float* __restrict__ Wfv,
    const float* __restrict__ vecs, const float* __restrict__ Wvk, const float* __restrict__ Wvv,
    const float* __restrict__ Wout1,
    unsigned short* __restrict__ fbf, unsigned short* __restrict__ wf,
    unsigned short* __restrict__ vbf, unsigned short* __restrict__ wv,
    float* __restrict__ W1p, float* __restrict__ hacc, float* __restrict__ qz)
{
    int i = blockIdx.x * 256 + threadIdx.x;
    if (i < 2490368) {                       // frames: 16384 x 152 items (4 cols each)
        int row = i / 152, k = (i - row * 152) * 4;
        us4 o = {0, 0, 0, 0};
        if (k < 600) {
            f32x4 v = *(const f32x4*)(frames + (size_t)row * 600 + k);
            o[0] = f2bf(v[0]); o[1] = f2bf(v[1]); o[2] = f2bf(v[2]); o[3] = f2bf(v[3]);
        }
        *(us4*)(fbf + (size_t)row * 608 + k) = o;
        return;
    }
    i -= 2490368;
    if (i < 155648) {                        // wf: 1024 x 152 (rows 0-511 Wfk, 512-1023 Wfv)
        int row = i / 152, k = (i - row * 152) * 4;
        const float* src = row < 512 ? Wfk + (size_t)row * 600 : Wfv + (size_t)(row - 512) * 600;
        us4 o = {0, 0, 0, 0};
        if (k < 600) {
            f32x4 v = *(const f32x4*)(src + k);
            o[0] = f2bf(v[0]); o[1] = f2bf(v[1]); o[2] = f2bf(v[2]); o[3] = f2bf(v[3]);
        }
        *(us4*)(wf + (size_t)row * 608 + k) = o;
        return;
    }
    i -= 155648;
    if (i < 1572864) {                       // vecs: 8192 x 192
        int row = i / 192, k = (i - row * 192) * 4;
        f32x4 v = *(const f32x4*)(vecs + (size_t)row * 768 + k);
        us4 o = {f2bf(v[0]), f2bf(v[1]), f2bf(v[2]), f2bf(v[3])};
        *(us4*)(vbf + (size_t)row * 768 + k) = o;
        return;
    }
    i -= 1572864;
    if (i < 196608) {                        // wv: 1024 x 192
        int row = i / 192, k = (i - row * 192) * 4;
        const float* src = row < 512 ? Wvk + (size_t)row * 768 : Wvv + (size_t)(row - 512) * 768;
        f32x4 v = *(const f32x4*)(src + k);
        us4 o = {f2bf(v[0]), f2bf(v[1]), f2bf(v[2]), f2bf(v[3])};
        *(us4*)(wv + (size_t)row * 768 + k) = o;
        return;
    }
    i -= 196608;
    if (i < 344064) {                        // W1p: 768 x 448 float4 items
        int r = i / 448, k = (i - r * 448) * 4;
        f32x4 o;
        #pragma unroll
        for (int j = 0; j < 4; ++j) {
            int kk = k + j;
            o[j] = kk < 1539 ? Wout1[(size_t)r * 1539 + kk] : 0.f;
        }
        *(f32x4*)(W1p + (size_t)r * 1792 + k) = o;
        return;
    }
    i -= 344064;
    if (i < 20480) {                         // zero h1acc+h2acc (81920 floats)
        f32x4 z = {0, 0, 0, 0};
        *(f32x4*)(hacc + (size_t)i * 4) = z;
        return;
    }
    i -= 20480;
    if (i < 16384) {                         // zero f_q_p|v_q_p (65536 floats)
        f32x4 z = {0, 0, 0, 0};
        *(f32x4*)(qz + (size_t)i * 4) = z;
    }
}

// ---------------------------------------------------------------- GEMM (m97 structure)
// C[m][n] = relu(sum_k A[m][k]*B[n][k]) in bf16; value-half (cols>=512) column
// sums per group are atomically accumulated into qout[g*512 + col-512].
__global__ __launch_bounds__(256) void gemm_bt_relu(
    const unsigned short* __restrict__ A, const unsigned short* __restrict__ B,
    unsigned short* __restrict__ C, int Kp, float* __restrict__ qout, int gshift)
{
    __shared__ alignas(16) unsigned short sA[128 * 32];
    __shared__ alignas(16) unsigned short sB[128 * 32];
    const int t = threadIdx.x;
    const int w = t >> 6, l = t & 63;
    const int bm = blockIdx.x >> 3, bn = blockIdx.x & 7;
    const int m0 = bm << 7, n0 = bn << 7;

    const int srow = t >> 2, sk0 = (t & 3) << 3;
    const unsigned short* gA = A + (size_t)(m0 + srow) * Kp + sk0;
    const unsigned short* gB = B + (size_t)(n0 + srow) * Kp + sk0;
    char* lA = (char*)sA + w * 1024;
    char* lB = (char*)sB + w * 1024;

    const int wr = w >> 1, wc = w & 1;
    const unsigned short* pA = sA + (size_t)((wr * 64 + (l & 15)) * 32 + ((l >> 4) << 3));
    const unsigned short* pB = sB + (size_t)((wc * 64 + (l & 15)) * 32 + ((l >> 4) << 3));

    f32x4 acc[4][4] = {};
    const int ksteps = Kp >> 5;
    for (int kt = 0; kt < ksteps; ++kt) {
        const unsigned short* ga = gA + kt * 32;
        const unsigned short* gb = gB + kt * 32;
        cp16(ga, lA);
        cp16(ga + (size_t)64 * Kp, lA + 4096);
        cp16(gb, lB);
        cp16(gb + (size_t)64 * Kp, lB + 4096);
        __syncthreads();
        bf16x8 af[4], bfr[4];
        #pragma unroll
        for (int i = 0; i < 4; ++i) {
            af[i]  = *(const bf16x8*)(pA + i * 512);
            bfr[i] = *(const bf16x8*)(pB + i * 512);
        }
        #pragma unroll
        for (int mi = 0; mi < 4; ++mi)
            #pragma unroll
            for (int ni = 0; ni < 4; ++ni)
                acc[mi][ni] = __builtin_amdgcn_mfma_f32_16x16x32_bf16(af[mi], bfr[ni], acc[mi][ni], 0, 0, 0);
        __syncthreads();
    }
    const int crow0 = m0 + wr * 64 + ((l >> 4) << 2);
    const int ccol0 = n0 + wc * 64 + (l & 15);
    #pragma unroll
    for (int mi = 0; mi < 4; ++mi)
        #pragma unroll
        for (int ni = 0; ni < 4; ++ni)
            #pragma unroll
            for (int j = 0; j < 4; ++j) {
                float v = acc[mi][ni][j];
                v = v > 0.f ? v : 0.f;
                C[(size_t)(crow0 + mi * 16 + j) * 1024 + (ccol0 + ni * 16)] = f2bf(v);
            }
    // fused per-group column sums of the value half
    if (n0 >= 512) {
        const int g = m0 >> gshift;
        float csum[4];
        #pragma unroll
        for (int ni = 0; ni < 4; ++ni) {
            float s = 0.f;
            #pragma unroll
            for (int mi = 0; mi < 4; ++mi)
                #pragma unroll
                for (int j = 0; j < 4; ++j)
                    s += fmaxf(acc[mi][ni][j], 0.f);
            s += __shfl_xor(s, 16, 64);
            s += __shfl_xor(s, 32, 64);
            csum[ni] = s;
        }
        if (l < 16) {
            #pragma unroll
            for (int ni = 0; ni < 4; ++ni)
                atomicAdd(&qout[g * 512 + (ccol0 - 512) + ni * 16], csum[ni]);
        }
    }
}

// ---------------------------------------------------------------- audio: a_v = relu(audios@Wav^T)
__global__ __launch_bounds__(256) void audio_kernel(
    const float* __restrict__ audios, const float* __restrict__ Wav,
    float* __restrict__ a_v, float* __restrict__ a_q_p)
{
    __shared__ float aud[128];
    const int t = threadIdx.x, b = blockIdx.x;
    if (t < 128) aud[t] = audios[b * 128 + t];
    __syncthreads();
    #pragma unroll
    for (int cc = 0; cc < 2; ++cc) {
        int c = 2 * t + cc;
        const float* wr = Wav + (size_t)c * 128;
        float s = 0.f;
        #pragma unroll
        for (int k4 = 0; k4 < 32; ++k4) {
            f32x4 wvv = *(const f32x4*)(wr + k4 * 4);
            s += wvv[0] * aud[k4 * 4] + wvv[1] * aud[k4 * 4 + 1]
               + wvv[2] * aud[k4 * 4 + 2] + wvv[3] * aud[k4 * 4 + 3];
        }
        s = s > 0.f ? s : 0.f;
        a_v[b * 512 + c] = s;
        a_q_p[b * 512 + c] = s;
    }
}

// ---------------------------------------------------------------- scores: one wave per frame
// sbuf[frame] = dot(K_half[frame], v_q_p[g]) / 512. Blocks 0..63 also zero fc|vc.
__global__ __launch_bounds__(256) void scores_kernel(
    const unsigned short* __restrict__ Cf, const unsigned short* __restrict__ Cv,
    const float* __restrict__ v_q_p, float* __restrict__ sbuf, float* __restrict__ fvz)
{
    const int t = threadIdx.x, bid = blockIdx.x;
    if (bid < 64) {                          // zero fc|vc (65536 floats)
        f32x4 z = {0, 0, 0, 0};
        ((f32x4*)fvz)[bid * 256 + t] = z;
    }
    const int w = t >> 6, l = t & 63;
    int frame, g, soff;
    const unsigned short* X;
    if (bid < 4096) { frame = bid * 4 + w; g = frame >> 8; X = Cf; soff = 0; }
    else            { frame = (bid - 4096) * 4 + w; g = frame >> 7; X = Cv; soff = 16384; }
    const float* vq = v_q_p + g * 512 + l * 8;
    f32x4 q0 = *(const f32x4*)vq;
    f32x4 q1 = *(const f32x4*)(vq + 4);
    u32x4 u = *(const u32x4*)(X + (size_t)frame * 1024 + l * 8);
    float acc = q0[0] * bf2f((unsigned short)(u[0] & 0xffff)) + q0[1] * bf2f((unsigned short)(u[0] >> 16))
              + q0[2] * bf2f((unsigned short)(u[1] & 0xffff)) + q0[3] * bf2f((unsigned short)(u[1] >> 16))
              + q1[0] * bf2f((unsigned short)(u[2] & 0xffff)) + q1[1] * bf2f((unsigned short)(u[2] >> 16))
              + q1[2] * bf2f((unsigned short)(u[3] & 0xffff)) + q1[3] * bf2f((unsigned short)(u[3] >> 16));
    #pragma unroll
    for (int m = 1; m < 64; m <<= 1) acc += __shfl_xor(acc, m, 64);
    if (l == 0) sbuf[soff + frame] = acc * (1.f / 512.f);
}

// ---------------------------------------------------------------- PV: softmax + weighted V sum
// grid: 512 f-blocks (g,chunk of 32 frames) + 256 v-blocks. atomicAdd into fc/vc.
__global__ __launch_bounds__(256) void pv_kernel(
    const unsigned short* __restrict__ Cf, const unsigned short* __restrict__ Cv,
    const float* __restrict__ sbuf, float* __restrict__ fc, float* __restrict__ vc)
{
    __shared__ float ws[256];
    __shared__ float red[256];
    const int t = threadIdx.x, bid = blockIdx.x;
    int g, chunk, NF, soff;
    const unsigned short* X;
    float* outp;
    if (bid < 512) { g = bid >> 3; chunk = bid & 7; NF = 256; X = Cf; soff = g * 256; outp = fc; }
    else { int b2 = bid - 512; g = b2 >> 2; chunk = b2 & 3; NF = 128; X = Cv; soff = 16384 + g * 128; outp = vc; }
    float s = (t < NF) ? sbuf[soff + t] : -1e30f;
    red[t] = s;
    __syncthreads();
    for (int st = 128; st > 0; st >>= 1) { if (t < st) red[t] = fmaxf(red[t], red[t + st]); __syncthreads(); }
    float m = red[0];
    __syncthreads();
    float e = (t < NF) ? __expf(s - m) : 0.f;
    ws[t] = e;
    red[t] = e;
    __syncthreads();
    for (int st = 128; st > 0; st >>= 1) { if (t < st) red[t] += red[t + st]; __syncthreads(); }
    float inv = 1.f / red[0];
    const int f0 = g * NF + chunk * 32;
    const unsigned int* q = (const unsigned int*)X + (size_t)f0 * 512 + 256 + t;
    float s0 = 0.f, s1 = 0.f;
    #pragma unroll 4
    for (int f = 0; f < 32; ++f) {
        float a = ws[chunk * 32 + f];
        unsigned u = q[(size_t)f * 512];
        s0 += a * bf2f((unsigned short)(u & 0xffff));
        s1 += a * bf2f((unsigned short)(u >> 16));
    }
    atomicAdd(&outp[g * 512 + 2 * t],     s0 * inv);
    atomicAdd(&outp[g * 512 + 2 * t + 1], s1 * inv);
}

// ---------------------------------------------------------------- batched GEMV body
// Y[b][row] += sum_{k in chunk} act(X[b][k]) * W[row][k]; 32 batches, 64 rows, 128 k per block
__device__ __forceinline__ void gemv_body(
    const float* __restrict__ X, int ldx, int dorelu,
    const float* __restrict__ W, int ldw, float* __restrict__ Y, int ldy,
    int nc, int kc, int bc)
{
    __shared__ float xs[4096];
    const int t = threadIdx.x;
    #pragma unroll
    for (int j = 0; j < 16; ++j) {
        int idx = t + j * 256;
        float v = X[(size_t)(bc * 32 + (idx >> 7)) * ldx + kc * 128 + (idx & 127)];
        xs[idx] = dorelu ? (v > 0.f ? v : 0.f) : v;
    }
    __syncthreads();
    const int r = t & 63, bg = t >> 6;
    const int row = nc * 64 + r;
    const float* wrow = W + (size_t)row * ldw + kc * 128;
    float acc[8] = {};
    #pragma unroll 8
    for (int k4 = 0; k4 < 32; ++k4) {
        f32x4 wvv = *(const f32x4*)(wrow + k4 * 4);
        #pragma unroll
        for (int bb = 0; bb < 8; ++bb) {
            f32x4 xv = *(const f32x4*)(xs + (bg * 8 + bb) * 128 + k4 * 4);
            acc[bb] += wvv[0] * xv[0] + wvv[1] * xv[1] + wvv[2] * xv[2] + wvv[3] * xv[3];
        }
    }
    #pragma unroll
    for (int bb = 0; bb < 8; ++bb)
        atomicAdd(&Y[(size_t)(bc * 32 + bg * 8 + bb) * ldy + row], acc[bb]);
}

// update: 3 ops x 8 nc x 4 kc x 2 bc = 192 blocks
__global__ __launch_bounds__(256) void update_kernel(
    const float* __restrict__ Wff_f, const float* __restrict__ Wff_v, const float* __restrict__ Wff_a,
    int iter, const float* __restrict__ fc, const float* __restrict__ vc, const float* __restrict__ a_v,
    float* __restrict__ f_q_p, float* __restrict__ v_q_p, float* __restrict__ a_q_p)
{
    int id = blockIdx.x;
    const int op = id >> 6; id &= 63;
    const int nc = id & 7, kc = (id >> 3) & 3, bc = id >> 5;
    const float* W = (op == 0 ? Wff_f : op == 1 ? Wff_v : Wff_a) + (size_t)iter * 262144;
    const float* X = op == 0 ? fc : op == 1 ? vc : a_v;
    float* Y = op == 0 ? f_q_p : op == 1 ? v_q_p : a_q_p;
    gemv_body(X, 512, 0, W, 512, Y, 512, nc, kc, bc);
}

// generic: grid = NC*KC*2
__global__ __launch_bounds__(256) void gemvb_kernel(
    const float* __restrict__ X, int ldx, int dorelu,
    const float* __restrict__ W, int ldw, float* __restrict__ Y, int ldy,
    int NC, int KC)
{
    int bid = blockIdx.x;
    const int nc = bid % NC; bid /= NC;
    const int kc = bid % KC;
    const int bc = bid / KC;
    gemv_body(X, ldx, dorelu, W, ldw, Y, ldy, nc, kc, bc);
}

// ---------------------------------------------------------------- normalize + build feats
__global__ __launch_bounds__(512) void normfeats_kernel(
    const float* __restrict__ a_q_p, const float* __restrict__ f_q_p, const float* __restrict__ v_q_p,
    const float* __restrict__ metas, float* __restrict__ feats)
{
    __shared__ float red[512];
    const int t = threadIdx.x, b = blockIdx.x;
    float a = a_q_p[b * 512 + t];
    red[t] = a;
    __syncthreads();
    for (int s = 256; s > 0; s >>= 1) { if (t < s) red[t] += red[t + s]; __syncthreads(); }
    float mean = red[0] * (1.f / 512.f);
    __syncthreads();
    float d = a - mean;
    red[t] = d * d;
    __syncthreads();
    for (int s = 256; s > 0; s >>= 1) { if (t < s) red[t] += red[t + s]; __syncthreads(); }
    float sd = sqrtf(red[0] * (1.f / 511.f));
    float* fr = feats + (size_t)b * 1792;
    fr[t]        = f_q_p[b * 512 + t];
    fr[512 + t]  = v_q_p[b * 512 + t];
    fr[1024 + t] = d / sd;
    if (t < 256) {
        float v = 0.f;
        if (t == 0) v = metas[b * 5 + 1] * (1.f / 1500.f);
        else if (t == 1) v = metas[b * 5 + 4] * 0.2f;
        else if (t == 2) {
            float du = metas[b * 5 + 3] - metas[b * 5 + 2];
            v = (du > 8000.f ? 100.f : du) * 0.01f;
        }
        fr[1536 + t] = v;
    }
}

// ---------------------------------------------------------------- MLP layers 3+4, one block per batch
__global__ __launch_bounds__(256) void mlp34_kernel(
    const float* __restrict__ h2acc, const float* __restrict__ W3, const float* __restrict__ W4,
    float* __restrict__ out)
{
    __shared__ float xs[512];
    __shared__ float part[256];
    __shared__ float h3[64];
    const int t = threadIdx.x, b = blockIdx.x;
    {
        float v0 = h2acc[(size_t)b * 512 + t];
        float v1 = h2acc[(size_t)b * 512 + 256 + t];
        xs[t] = v0 > 0.f ? v0 : 0.f;
        xs[256 + t] = v1 > 0.f ? v1 : 0.f;
    }
    __syncthreads();
    const int r = t & 63, q = t >> 6;
    const float* wrow = W3 + (size_t)r * 512 + q * 128;
    float acc = 0.f;
    #pragma unroll 8
    for (int k4 = 0; k4 < 32; ++k4) {
        f32x4 wvv = *(const f32x4*)(wrow + k4 * 4);
        f32x4 xv  = *(const f32x4*)(xs + q * 128 + k4 * 4);
        acc += wvv[0] * xv[0] + wvv[1] * xv[1] + wvv[2] * xv[2] + wvv[3] * xv[3];
    }
    part[t] = acc;
    __syncthreads();
    if (t < 64) {
        float h = part[t] + part[t + 64] + part[t + 128] + part[t + 192];
        h3[t] = h > 0.f ? h : 0.f;
    }
    __syncthreads();
    if (t < 64) {
        float v = h3[t] * W4[t];
        #pragma unroll
        for (int m = 1; m < 64; m <<= 1) v += __shfl_xor(v, m, 64);
        if (t == 0) out[b] = 1.f / (1.f + __expf(-v));
    }
}

// ---------------------------------------------------------------- launch
extern "C" void kernel_launch(void* const* d_in, const int* in_sizes, int n_in,
                              void* d_out, int out_size, void* d_ws, size_t ws_size,
                              hipStream_t stream)
{
    const float* metas  = (const float*)d_in[0];
    const float* frames = (const float*)d_in[2];
    const float* vecs   = (const float*)d_in[4];
    const float* audios = (const float*)d_in[6];
    const float* Wfk   = (const float*)d_in[8];
    const float* Wfv   = (const float*)d_in[9];
    const float* Wvk   = (const float*)d_in[10];
    const float* Wvv   = (const float*)d_in[11];
    const float* Wav   = (const float*)d_in[12];
    const float* Wff_f = (const float*)d_in[13];
    const float* Wff_v = (const float*)d_in[14];
    const float* Wff_a = (const float*)d_in[15];
    const float* Wout1 = (const float*)d_in[16];
    const float* Wout2 = (const float*)d_in[17];
    const float* Wout3 = (const float*)d_in[18];
    const float* Wout4 = (const float*)d_in[19];
    float* out = (float*)d_out;

    char* p = (char*)d_ws;
    auto alloc = [&](size_t n) { char* r = p; p += (n + 255) & ~(size_t)255; return r; };
    unsigned short* fbf = (unsigned short*)alloc(16384ull * 608 * 2);
    unsigned short* wf  = (unsigned short*)alloc(1024ull * 608 * 2);
    unsigned short* vbf = (unsigned short*)alloc(8192ull * 768 * 2);
    unsigned short* wv  = (unsigned short*)alloc(1024ull * 768 * 2);
    unsigned short* Cf  = (unsigned short*)alloc(16384ull * 1024 * 2);
    unsigned short* Cv  = (unsigned short*)alloc(8192ull * 1024 * 2);
    float* W1p   = (float*)alloc(768ull * 1792 * 4);
    float* feats = (float*)alloc(64ull * 1792 * 4);
    float* qbuf  = (float*)alloc(2ull * 64 * 512 * 4);     // f_q_p | v_q_p (zeroed in prep)
    float* f_q_p = qbuf;
    float* v_q_p = qbuf + 64 * 512;
    float* a_q_p = (float*)alloc(64ull * 512 * 4);
    float* a_v   = (float*)alloc(64ull * 512 * 4);
    float* fvc   = (float*)alloc(2ull * 64 * 512 * 4);     // fc | vc (zeroed in scores)
    float* fcb   = fvc;
    float* vcb   = fvc + 64 * 512;
    float* hacc  = (float*)alloc(81920ull * 4);            // h1acc (64*768) | h2acc (64*512)
    float* h1acc = hacc;
    float* h2acc = hacc + 64 * 768;
    float* sbuf  = (float*)alloc(24576ull * 4);            // f scores [16384] | v scores [8192]

    prep_kernel<<<18736, 256, 0, stream>>>(frames, Wfk, Wfv, vecs, Wvk, Wvv, Wout1,
                                           fbf, wf, vbf, wv, W1p, hacc, qbuf);
    audio_kernel<<<64, 256, 0, stream>>>(audios, Wav, a_v, a_q_p);
    gemm_bt_relu<<<1024, 256, 0, stream>>>(fbf, wf, Cf, 608, f_q_p, 8);
    gemm_bt_relu<<<512, 256, 0, stream>>>(vbf, wv, Cv, 768, v_q_p, 7);
    for (int i = 0; i < 2; ++i) {
        scores_kernel<<<6144, 256, 0, stream>>>(Cf, Cv, v_q_p, sbuf, fvc);
        pv_kernel<<<768, 256, 0, stream>>>(Cf, Cv, sbuf, fcb, vcb);
        update_kernel<<<192, 256, 0, stream>>>(Wff_f, Wff_v, Wff_a, i, fcb, vcb, a_v,
                                               f_q_p, v_q_p, a_q_p);
    }
    normfeats_kernel<<<64, 512, 0, stream>>>(a_q_p, f_q_p, v_q_p, metas, feats);
    gemvb_kernel<<<336, 256, 0, stream>>>(feats, 1792, 0, W1p, 1792, h1acc, 768, 12, 14);
    gemvb_kernel<<<96, 256, 0, stream>>>(h1acc, 768, 1, Wout2, 768, h2acc, 512, 8, 6);
    mlp34_kernel<<<64, 256, 0, stream>>>(h2acc, Wout3, Wout4, out);
}

// Round 3
// 189.826 us; speedup vs baseline: 2.0217x; 1.0143x over previous
//
#include <hip/hip_runtime.h>
#include <hip/hip_bf16.h>

typedef __attribute__((ext_vector_type(4))) float f32x4;
typedef __attribute__((ext_vector_type(8))) __bf16 bf16x8;
typedef __attribute__((ext_vector_type(4))) unsigned short us4;
typedef __attribute__((ext_vector_type(8))) unsigned short us8;
typedef __attribute__((ext_vector_type(4))) unsigned int u32x4;

#define LDS_AS __attribute__((address_space(3)))
#define GLB_AS __attribute__((address_space(1)))

__device__ __forceinline__ unsigned short f2bf(float f) {
    unsigned u = __builtin_bit_cast(unsigned, f);
    return (unsigned short)((u + 0x7FFFu + ((u >> 16) & 1u)) >> 16);  // RNE
}
__device__ __forceinline__ float bf2f(unsigned short h) {
    return __builtin_bit_cast(float, (unsigned)h << 16);
}
__device__ __forceinline__ void cp16(const void* g, void* l) {
    __builtin_amdgcn_global_load_lds((const GLB_AS unsigned int*)g,
                                     (LDS_AS unsigned int*)l, 16, 0, 0);
}

// ---------------------------------------------------------------- prep (+audio)
// casts frames/vecs/weights to bf16 (frames K padded 600->608), pads Wout1
// [768][1539] -> [768][1792], zeroes h1acc/h2acc + f_q_p/v_q_p, computes a_v.
#define NPREP 10112
__global__ __launch_bounds__(256) void prep_kernel(
    const float* __restrict__ frames, const float* __restrict__ Wfk, const float* __restrict__ Wfv,
    const float* __restrict__ vecs, const float* __restrict__ Wvk, const float* __restrict__ Wvv,
    const float* __restrict__ Wout1, const float* __restrict__ audios, const float* __restrict__ Wav,
    unsigned short* __restrict__ fbf, unsigned short* __restrict__ wf,
    unsigned short* __restrict__ vbf, unsigned short* __restrict__ wv,
    float* __restrict__ W1p, float* __restrict__ hacc, float* __restrict__ qz,
    float* __restrict__ a_v, float* __restrict__ a_q_p)
{
    __shared__ float aud[128];
    const int t = threadIdx.x;
    if (blockIdx.x >= NPREP) {               // audio: a_v = relu(audios @ Wav^T)
        const int b = blockIdx.x - NPREP;
        if (t < 128) aud[t] = audios[b * 128 + t];
        __syncthreads();
        #pragma unroll
        for (int cc = 0; cc < 2; ++cc) {
            int c = 2 * t + cc;
            const float* wr = Wav + (size_t)c * 128;
            float s = 0.f;
            #pragma unroll
            for (int k4 = 0; k4 < 32; ++k4) {
                f32x4 wvv = *(const f32x4*)(wr + k4 * 4);
                s += wvv[0] * aud[k4 * 4] + wvv[1] * aud[k4 * 4 + 1]
                   + wvv[2] * aud[k4 * 4 + 2] + wvv[3] * aud[k4 * 4 + 3];
            }
            s = s > 0.f ? s : 0.f;
            a_v[b * 512 + c] = s;
            a_q_p[b * 512 + c] = s;
        }
        return;
    }
    int i = blockIdx.x * 256 + t;
    if (i < 1245184) {                       // frames: 16384 x 76 items (8 cols each)
        int row = i / 76, k = (i - row * 76) * 8;
        us8 o = {0, 0, 0, 0, 0, 0, 0, 0};
        if (k < 600) {
            const float* s = frames + (size_t)row * 600 + k;
            f32x4 v0 = *(const f32x4*)s;
            f32x4 v1 = *(const f32x4*)(s + 4);
            o[0] = f2bf(v0[0]); o[1] = f2bf(v0[1]); o[2] = f2bf(v0[2]); o[3] = f2bf(v0[3]);
            o[4] = f2bf(v1[0]); o[5] = f2bf(v1[1]); o[6] = f2bf(v1[2]); o[7] = f2bf(v1[3]);
        }
        *(us8*)(fbf + (size_t)row * 608 + k) = o;
        return;
    }
    i -= 1245184;
    if (i < 77824) {                         // wf: 1024 x 76 (rows 0-511 Wfk, 512-1023 Wfv)
        int row = i / 76, k = (i - row * 76) * 8;
        const float* src = row < 512 ? Wfk + (size_t)row * 600 : Wfv + (size_t)(row - 512) * 600;
        us8 o = {0, 0, 0, 0, 0, 0, 0, 0};
        if (k < 600) {
            f32x4 v0 = *(const f32x4*)(src + k);
            f32x4 v1 = *(const f32x4*)(src + k + 4);
            o[0] = f2bf(v0[0]); o[1] = f2bf(v0[1]); o[2] = f2bf(v0[2]); o[3] = f2bf(v0[3]);
            o[4] = f2bf(v1[0]); o[5] = f2bf(v1[1]); o[6] = f2bf(v1[2]); o[7] = f2bf(v1[3]);
        }
        *(us8*)(wf + (size_t)row * 608 + k) = o;
        return;
    }
    i -= 77824;
    if (i < 786432) {                        // vecs: 8192 x 96
        int row = i / 96, k = (i - row * 96) * 8;
        const float* s = vecs + (size_t)row * 768 + k;
        f32x4 v0 = *(const f32x4*)s;
        f32x4 v1 = *(const f32x4*)(s + 4);
        us8 o = {f2bf(v0[0]), f2bf(v0[1]), f2bf(v0[2]), f2bf(v0[3]),
                 f2bf(v1[0]), f2bf(v1[1]), f2bf(v1[2]), f2bf(v1[3])};
        *(us8*)(vbf + (size_t)row * 768 + k) = o;
        return;
    }
    i -= 786432;
    if (i < 98304) {                         // wv: 1024 x 96
        int row = i / 96, k = (i - row * 96) * 8;
        const float* src = (row < 512 ? Wvk + (size_t)row * 768
                                      : Wvv + (size_t)(row - 512) * 768) + k;
        f32x4 v0 = *(const f32x4*)src;
        f32x4 v1 = *(const f32x4*)(src + 4);
        us8 o = {f2bf(v0[0]), f2bf(v0[1]), f2bf(v0[2]), f2bf(v0[3]),
                 f2bf(v1[0]), f2bf(v1[1]), f2bf(v1[2]), f2bf(v1[3])};
        *(us8*)(wv + (size_t)row * 768 + k) = o;
        return;
    }
    i -= 98304;
    if (i < 344064) {                        // W1p: 768 x 448 float4 items
        int r = i / 448, k = (i - r * 448) * 4;
        f32x4 o;
        #pragma unroll
        for (int j = 0; j < 4; ++j) {
            int kk = k + j;
            o[j] = kk < 1539 ? Wout1[(size_t)r * 1539 + kk] : 0.f;
        }
        *(f32x4*)(W1p + (size_t)r * 1792 + k) = o;
        return;
    }
    i -= 344064;
    if (i < 20480) {                         // zero h1acc+h2acc (81920 floats)
        f32x4 z = {0, 0, 0, 0};
        *(f32x4*)(hacc + (size_t)i * 4) = z;
        return;
    }
    i -= 20480;
    if (i < 16384) {                         // zero f_q_p|v_q_p (65536 floats)
        f32x4 z = {0, 0, 0, 0};
        *(f32x4*)(qz + (size_t)i * 4) = z;
    }
}

// ---------------------------------------------------------------- GEMM (m97 structure + T1 swizzle)
// C[m][n] = relu(sum_k A[m][k]*B[n][k]) in bf16; value-half (cols>=512) column
// sums per group are atomically accumulated into qout[g*512 + col-512].
__global__ __launch_bounds__(256) void gemm_bt_relu(
    const unsigned short* __restrict__ A, const unsigned short* __restrict__ B,
    unsigned short* __restrict__ C, int Kp, float* __restrict__ qout, int gshift)
{
    __shared__ alignas(16) unsigned short sA[128 * 32];
    __shared__ alignas(16) unsigned short sB[128 * 32];
    const int t = threadIdx.x;
    const int w = t >> 6, l = t & 63;
    // XCD-aware bijective swizzle (nwg % 8 == 0): each XCD gets a contiguous
    // chunk of tiles so the 8 bn-blocks sharing an A-tile hit the same L2.
    const int nwg = gridDim.x;
    const int swz = (blockIdx.x & 7) * (nwg >> 3) + (blockIdx.x >> 3);
    const int bm = swz >> 3, bn = swz & 7;
    const int m0 = bm << 7, n0 = bn << 7;

    const int srow = t >> 2, sk0 = (t & 3) << 3;
    const unsigned short* gA = A + (size_t)(m0 + srow) * Kp + sk0;
    const unsigned short* gB = B + (size_t)(n0 + srow) * Kp + sk0;
    char* lA = (char*)sA + w * 1024;
    char* lB = (char*)sB + w * 1024;

    const int wr = w >> 1, wc = w & 1;
    const unsigned short* pA = sA + (size_t)((wr * 64 + (l & 15)) * 32 + ((l >> 4) << 3));
    const unsigned short* pB = sB + (size_t)((wc * 64 + (l & 15)) * 32 + ((l >> 4) << 3));

    f32x4 acc[4][4] = {};
    const int ksteps = Kp >> 5;
    for (int kt = 0; kt < ksteps; ++kt) {
        const unsigned short* ga = gA + kt * 32;
        const unsigned short* gb = gB + kt * 32;
        cp16(ga, lA);
        cp16(ga + (size_t)64 * Kp, lA + 4096);
        cp16(gb, lB);
        cp16(gb + (size_t)64 * Kp, lB + 4096);
        __syncthreads();
        bf16x8 af[4], bfr[4];
        #pragma unroll
        for (int i = 0; i < 4; ++i) {
            af[i]  = *(const bf16x8*)(pA + i * 512);
            bfr[i] = *(const bf16x8*)(pB + i * 512);
        }
        #pragma unroll
        for (int mi = 0; mi < 4; ++mi)
            #pragma unroll
            for (int ni = 0; ni < 4; ++ni)
                acc[mi][ni] = __builtin_amdgcn_mfma_f32_16x16x32_bf16(af[mi], bfr[ni], acc[mi][ni], 0, 0, 0);
        __syncthreads();
    }
    const int crow0 = m0 + wr * 64 + ((l >> 4) << 2);
    const int ccol0 = n0 + wc * 64 + (l & 15);
    #pragma unroll
    for (int mi = 0; mi < 4; ++mi)
        #pragma unroll
        for (int ni = 0; ni < 4; ++ni)
            #pragma unroll
            for (int j = 0; j < 4; ++j) {
                float v = acc[mi][ni][j];
                v = v > 0.f ? v : 0.f;
                C[(size_t)(crow0 + mi * 16 + j) * 1024 + (ccol0 + ni * 16)] = f2bf(v);
            }
    // fused per-group column sums of the value half
    if (n0 >= 512) {
        const int g = m0 >> gshift;
        float csum[4];
        #pragma unroll
        for (int ni = 0; ni < 4; ++ni) {
            float s = 0.f;
            #pragma unroll
            for (int mi = 0; mi < 4; ++mi)
                #pragma unroll
                for (int j = 0; j < 4; ++j)
                    s += fmaxf(acc[mi][ni][j], 0.f);
            s += __shfl_xor(s, 16, 64);
            s += __shfl_xor(s, 32, 64);
            csum[ni] = s;
        }
        if (l < 16) {
            #pragma unroll
            for (int ni = 0; ni < 4; ++ni)
                atomicAdd(&qout[g * 512 + (ccol0 - 512) + ni * 16], csum[ni]);
        }
    }
}

// ---------------------------------------------------------------- scores: one wave per frame
// sbuf[frame] = dot(K_half[frame], v_q_p[g]) / 512. Blocks 0..63 also zero fc|vc.
__global__ __launch_bounds__(256) void scores_kernel(
    const unsigned short* __restrict__ Cf, const unsigned short* __restrict__ Cv,
    const float* __restrict__ v_q_p, float* __restrict__ sbuf, float* __restrict__ fvz)
{
    const int t = threadIdx.x, bid = blockIdx.x;
    if (bid < 64) {                          // zero fc|vc (65536 floats)
        f32x4 z = {0, 0, 0, 0};
        ((f32x4*)fvz)[bid * 256 + t] = z;
    }
    const int w = t >> 6, l = t & 63;
    int frame, g, soff;
    const unsigned short* X;
    if (bid < 4096) { frame = bid * 4 + w; g = frame >> 8; X = Cf; soff = 0; }
    else            { frame = (bid - 4096) * 4 + w; g = frame >> 7; X = Cv; soff = 16384; }
    const float* vq = v_q_p + g * 512 + l * 8;
    f32x4 q0 = *(const f32x4*)vq;
    f32x4 q1 = *(const f32x4*)(vq + 4);
    u32x4 u = *(const u32x4*)(X + (size_t)frame * 1024 + l * 8);
    float acc = q0[0] * bf2f((unsigned short)(u[0] & 0xffff)) + q0[1] * bf2f((unsigned short)(u[0] >> 16))
              + q0[2] * bf2f((unsigned short)(u[1] & 0xffff)) + q0[3] * bf2f((unsigned short)(u[1] >> 16))
              + q1[0] * bf2f((unsigned short)(u[2] & 0xffff)) + q1[1] * bf2f((unsigned short)(u[2] >> 16))
              + q1[2] * bf2f((unsigned short)(u[3] & 0xffff)) + q1[3] * bf2f((unsigned short)(u[3] >> 16));
    #pragma unroll
    for (int m = 1; m < 64; m <<= 1) acc += __shfl_xor(acc, m, 64);
    if (l == 0) sbuf[soff + frame] = acc * (1.f / 512.f);
}

// ---------------------------------------------------------------- PV: softmax + weighted V sum
// grid: 512 f-blocks (g,chunk of 32 frames) + 256 v-blocks. atomicAdd into fc/vc.
__global__ __launch_bounds__(256) void pv_kernel(
    const unsigned short* __restrict__ Cf, const unsigned short* __restrict__ Cv,
    const float* __restrict__ sbuf, float* __restrict__ fc, float* __restrict__ vc)
{
    __shared__ float ws[256];
    __shared__ float red[256];
    const int t = threadIdx.x, bid = blockIdx.x;
    int g, chunk, NF, soff;
    const unsigned short* X;
    float* outp;
    if (bid < 512) { g = bid >> 3; chunk = bid & 7; NF = 256; X = Cf; soff = g * 256; outp = fc; }
    else { int b2 = bid - 512; g = b2 >> 2; chunk = b2 & 3; NF = 128; X = Cv; soff = 16384 + g * 128; outp = vc; }
    float s = (t < NF) ? sbuf[soff + t] : -1e30f;
    red[t] = s;
    __syncthreads();
    for (int st = 128; st > 0; st >>= 1) { if (t < st) red[t] = fmaxf(red[t], red[t + st]); __syncthreads(); }
    float m = red[0];
    __syncthreads();
    float e = (t < NF) ? __expf(s - m) : 0.f;
    ws[t] = e;
    red[t] = e;
    __syncthreads();
    for (int st = 128; st > 0; st >>= 1) { if (t < st) red[t] += red[t + st]; __syncthreads(); }
    float inv = 1.f / red[0];
    const int f0 = g * NF + chunk * 32;
    const unsigned int* q = (const unsigned int*)X + (size_t)f0 * 512 + 256 + t;
    float s0 = 0.f, s1 = 0.f;
    #pragma unroll 4
    for (int f = 0; f < 32; ++f) {
        float a = ws[chunk * 32 + f];
        unsigned u = q[(size_t)f * 512];
        s0 += a * bf2f((unsigned short)(u & 0xffff));
        s1 += a * bf2f((unsigned short)(u >> 16));
    }
    atomicAdd(&outp[g * 512 + 2 * t],     s0 * inv);
    atomicAdd(&outp[g * 512 + 2 * t + 1], s1 * inv);
}

// ---------------------------------------------------------------- batched GEMV body
// Y[b][row] += sum_{k in chunk} act(X[b][k]) * W[row][k]; 32 batches, 64 rows, 128 k per block
__device__ __forceinline__ void gemv_body(
    const float* __restrict__ X, int ldx, int dorelu,
    const float* __restrict__ W, int ldw, float* __restrict__ Y, int ldy,
    int nc, int kc, int bc)
{
    __shared__ float xs[4096];
    const int t = threadIdx.x;
    #pragma unroll
    for (int j = 0; j < 16; ++j) {
        int idx = t + j * 256;
        float v = X[(size_t)(bc * 32 + (idx >> 7)) * ldx + kc * 128 + (idx & 127)];
        xs[idx] = dorelu ? (v > 0.f ? v : 0.f) : v;
    }
    __syncthreads();
    const int r = t & 63, bg = t >> 6;
    const int row = nc * 64 + r;
    const float* wrow = W + (size_t)row * ldw + kc * 128;
    float acc[8] = {};
    #pragma unroll 8
    for (int k4 = 0; k4 < 32; ++k4) {
        f32x4 wvv = *(const f32x4*)(wrow + k4 * 4);
        #pragma unroll
        for (int bb = 0; bb < 8; ++bb) {
            f32x4 xv = *(const f32x4*)(xs + (bg * 8 + bb) * 128 + k4 * 4);
            acc[bb] += wvv[0] * xv[0] + wvv[1] * xv[1] + wvv[2] * xv[2] + wvv[3] * xv[3];
        }
    }
    #pragma unroll
    for (int bb = 0; bb < 8; ++bb)
        atomicAdd(&Y[(size_t)(bc * 32 + bg * 8 + bb) * ldy + row], acc[bb]);
}

// update: 3 ops x 8 nc x 4 kc x 2 bc = 192 blocks
__global__ __launch_bounds__(256) void update_kernel(
    const float* __restrict__ Wff_f, const float* __restrict__ Wff_v, const float* __restrict__ Wff_a,
    int iter, const float* __restrict__ fc, const float* __restrict__ vc, const float* __restrict__ a_v,
    float* __restrict__ f_q_p, float* __restrict__ v_q_p, float* __restrict__ a_q_p)
{
    int id = blockIdx.x;
    const int op = id >> 6; id &= 63;
    const int nc = id & 7, kc = (id >> 3) & 3, bc = id >> 5;
    const float* W = (op == 0 ? Wff_f : op == 1 ? Wff_v : Wff_a) + (size_t)iter * 262144;
    const float* X = op == 0 ? fc : op == 1 ? vc : a_v;
    float* Y = op == 0 ? f_q_p : op == 1 ? v_q_p : a_q_p;
    gemv_body(X, 512, 0, W, 512, Y, 512, nc, kc, bc);
}

// generic: grid = NC*KC*2
__global__ __launch_bounds__(256) void gemvb_kernel(
    const float* __restrict__ X, int ldx, int dorelu,
    const float* __restrict__ W, int ldw, float* __restrict__ Y, int ldy,
    int NC, int KC)
{
    int bid = blockIdx.x;
    const int nc = bid % NC; bid /= NC;
    const int kc = bid % KC;
    const int bc = bid / KC;
    gemv_body(X, ldx, dorelu, W, ldw, Y, ldy, nc, kc, bc);
}

// ---------------------------------------------------------------- normalize + build feats
__global__ __launch_bounds__(512) void normfeats_kernel(
    const float* __restrict__ a_q_p, const float* __restrict__ f_q_p, const float* __restrict__ v_q_p,
    const float* __restrict__ metas, float* __restrict__ feats)
{
    __shared__ float red[512];
    const int t = threadIdx.x, b = blockIdx.x;
    float a = a_q_p[b * 512 + t];
    red[t] = a;
    __syncthreads();
    for (int s = 256; s > 0; s >>= 1) { if (t < s) red[t] += red[t + s]; __syncthreads(); }
    float mean = red[0] * (1.f / 512.f);
    __syncthreads();
    float d = a - mean;
    red[t] = d * d;
    __syncthreads();
    for (int s = 256; s > 0; s >>= 1) { if (t < s) red[t] += red[t + s]; __syncthreads(); }
    float sd = sqrtf(red[0] * (1.f / 511.f));
    float* fr = feats + (size_t)b * 1792;
    fr[t]        = f_q_p[b * 512 + t];
    fr[512 + t]  = v_q_p[b * 512 + t];
    fr[1024 + t] = d / sd;
    if (t < 256) {
        float v = 0.f;
        if (t == 0) v = metas[b * 5 + 1] * (1.f / 1500.f);
        else if (t == 1) v = metas[b * 5 + 4] * 0.2f;
        else if (t == 2) {
            float du = metas[b * 5 + 3] - metas[b * 5 + 2];
            v = (du > 8000.f ? 100.f : du) * 0.01f;
        }
        fr[1536 + t] = v;
    }
}

// ---------------------------------------------------------------- MLP layers 3+4, one block per batch
__global__ __launch_bounds__(256) void mlp34_kernel(
    const float* __restrict__ h2acc, const float* __restrict__ W3, const float* __restrict__ W4,
    float* __restrict__ out)
{
    __shared__ float xs[512];
    __shared__ float part[256];
    __shared__ float h3[64];
    const int t = threadIdx.x, b = blockIdx.x;
    {
        float v0 = h2acc[(size_t)b * 512 + t];
        float v1 = h2acc[(size_t)b * 512 + 256 + t];
        xs[t] = v0 > 0.f ? v0 : 0.f;
        xs[256 + t] = v1 > 0.f ? v1 : 0.f;
    }
    __syncthreads();
    const int r = t & 63, q = t >> 6;
    const float* wrow = W3 + (size_t)r * 512 + q * 128;
    float acc = 0.f;
    #pragma unroll 8
    for (int k4 = 0; k4 < 32; ++k4) {
        f32x4 wvv = *(const f32x4*)(wrow + k4 * 4);
        f32x4 xv  = *(const f32x4*)(xs + q * 128 + k4 * 4);
        acc += wvv[0] * xv[0] + wvv[1] * xv[1] + wvv[2] * xv[2] + wvv[3] * xv[3];
    }
    part[t] = acc;
    __syncthreads();
    if (t < 64) {
        float h = part[t] + part[t + 64] + part[t + 128] + part[t + 192];
        h3[t] = h > 0.f ? h : 0.f;
    }
    __syncthreads();
    if (t < 64) {
        float v = h3[t] * W4[t];
        #pragma unroll
        for (int m = 1; m < 64; m <<= 1) v += __shfl_xor(v, m, 64);
        if (t == 0) out[b] = 1.f / (1.f + __expf(-v));
    }
}

// ---------------------------------------------------------------- launch
extern "C" void kernel_launch(void* const* d_in, const int* in_sizes, int n_in,
                              void* d_out, int out_size, void* d_ws, size_t ws_size,
                              hipStream_t stream)
{
    const float* metas  = (const float*)d_in[0];
    const float* frames = (const float*)d_in[2];
    const float* vecs   = (const float*)d_in[4];
    const float* audios = (const float*)d_in[6];
    const float* Wfk   = (const float*)d_in[8];
    const float* Wfv   = (const float*)d_in[9];
    const float* Wvk   = (const float*)d_in[10];
    const float* Wvv   = (const float*)d_in[11];
    const float* Wav   = (const float*)d_in[12];
    const float* Wff_f = (const float*)d_in[13];
    const float* Wff_v = (const float*)d_in[14];
    const float* Wff_a = (const float*)d_in[15];
    const float* Wout1 = (const float*)d_in[16];
    const float* Wout2 = (const float*)d_in[17];
    const float* Wout3 = (const float*)d_in[18];
    const float* Wout4 = (const float*)d_in[19];
    float* out = (float*)d_out;

    char* p = (char*)d_ws;
    auto alloc = [&](size_t n) { char* r = p; p += (n + 255) & ~(size_t)255; return r; };
    unsigned short* fbf = (unsigned short*)alloc(16384ull * 608 * 2);
    unsigned short* wf  = (unsigned short*)alloc(1024ull * 608 * 2);
    unsigned short* vbf = (unsigned short*)alloc(8192ull * 768 * 2);
    unsigned short* wv  = (unsigned short*)alloc(1024ull * 768 * 2);
    unsigned short* Cf  = (unsigned short*)alloc(16384ull * 1024 * 2);
    unsigned short* Cv  = (unsigned short*)alloc(8192ull * 1024 * 2);
    float* W1p   = (float*)alloc(768ull * 1792 * 4);
    float* feats = (float*)alloc(64ull * 1792 * 4);
    float* qbuf  = (float*)alloc(2ull * 64 * 512 * 4);     // f_q_p | v_q_p (zeroed in prep)
    float* f_q_p = qbuf;
    float* v_q_p = qbuf + 64 * 512;
    float* a_q_p = (float*)alloc(64ull * 512 * 4);
    float* a_v   = (float*)alloc(64ull * 512 * 4);
    float* fvc   = (float*)alloc(2ull * 64 * 512 * 4);     // fc | vc (zeroed in scores)
    float* fcb   = fvc;
    float* vcb   = fvc + 64 * 512;
    float* hacc  = (float*)alloc(81920ull * 4);            // h1acc (64*768) | h2acc (64*512)
    float* h1acc = hacc;
    float* h2acc = hacc + 64 * 768;
    float* sbuf  = (float*)alloc(24576ull * 4);            // f scores [16384] | v scores [8192]

    prep_kernel<<<NPREP + 64, 256, 0, stream>>>(frames, Wfk, Wfv, vecs, Wvk, Wvv, Wout1,
                                                audios, Wav, fbf, wf, vbf, wv, W1p, hacc,
                                                qbuf, a_v, a_q_p);
    gemm_bt_relu<<<1024, 256, 0, stream>>>(fbf, wf, Cf, 608, f_q_p, 8);
    gemm_bt_relu<<<512, 256, 0, stream>>>(vbf, wv, Cv, 768, v_q_p, 7);
    for (int i = 0; i < 2; ++i) {
        scores_kernel<<<6144, 256, 0, stream>>>(Cf, Cv, v_q_p, sbuf, fvc);
        pv_kernel<<<768, 256, 0, stream>>>(Cf, Cv, sbuf, fcb, vcb);
        update_kernel<<<192, 256, 0, stream>>>(Wff_f, Wff_v, Wff_a, i, fcb, vcb, a_v,
                                               f_q_p, v_q_p, a_q_p);
    }
    normfeats_kernel<<<64, 512, 0, stream>>>(a_q_p, f_q_p, v_q_p, metas, feats);
    gemvb_kernel<<<336, 256, 0, stream>>>(feats, 1792, 0, W1p, 1792, h1acc, 768, 12, 14);
    gemvb_kernel<<<96, 256, 0, stream>>>(h1acc, 768, 1, Wout2, 768, h2acc, 512, 8, 6);
    mlp34_kernel<<<64, 256, 0, stream>>>(h2acc, Wout3, Wout4, out);
}